// Round 1
// baseline (1038.493 us; speedup 1.0000x reference)
//
#include <hip/hip_runtime.h>

// ---------------------------------------------------------------------------
// DNANet: 3-layer dynamic-neighborhood-attention graph conv on MI355X.
// N=50000 nodes, E=600000 edges (+N self loops), IN_C=128, HID=64, HEADS=4,
// d=16, OUT_C=16. fp32 throughout.
//
// Workspace layout (floats):
//   dinv : N            (deg -> rsqrt(deg))
//   q    : N*64         (query of newest slice, rewritten each layer)
//   K    : N*3*64       (key cache, slices 0..2, layout [node][l][c])
//   V    : N*3*64       (value cache)
//   sA   : N*64         (slice ping)
//   sB   : N*64         (slice pong)
// Total = N*577 floats = 115.4 MB.
// ---------------------------------------------------------------------------

__global__ __launch_bounds__(256) void set_ones_k(float* __restrict__ deg, int n) {
    int i = blockIdx.x * 256 + threadIdx.x;
    if (i < n) deg[i] = 1.0f;   // self-loop contributes 1 to every node's degree
}

__global__ __launch_bounds__(256) void count_deg_k(const int* __restrict__ dst,
                                                   float* __restrict__ deg, int E) {
    int e = blockIdx.x * 256 + threadIdx.x;
    if (e < E) atomicAdd(&deg[dst[e]], 1.0f);
}

__global__ __launch_bounds__(256) void finish_dinv_k(float* __restrict__ deg, int n) {
    int i = blockIdx.x * 256 + threadIdx.x;
    if (i < n) deg[i] = rsqrtf(deg[i]);   // deg >= 1 always (self loops)
}

// y[N x 64] = x[N x 128] @ W[128 x 64] + b
__global__ __launch_bounds__(256) void lin128_64_k(const float* __restrict__ x,
                                                   const float* __restrict__ W,
                                                   const float* __restrict__ b,
                                                   float* __restrict__ y, int N) {
    __shared__ float sW[128 * 64];
    __shared__ float sb[64];
    for (int i = threadIdx.x; i < 128 * 64; i += 256) sW[i] = W[i];
    if (threadIdx.x < 64) sb[threadIdx.x] = b[threadIdx.x];
    __syncthreads();
    int row = blockIdx.x * 4 + (threadIdx.x >> 6);
    int c   = threadIdx.x & 63;
    if (row >= N) return;
    const float* xr = x + (size_t)row * 128;
    float acc = sb[c];
#pragma unroll 16
    for (int k = 0; k < 128; ++k) acc = fmaf(xr[k], sW[k * 64 + c], acc);
    y[(size_t)row * 64 + c] = acc;
}

// From slice xs (N x 64): q = xs@Wq+bq ; K[:,l,:] = xs@Wk+bk ; V[:,l,:] = xs@Wv+bv
__global__ __launch_bounds__(256) void qkv64_k(const float* __restrict__ xs,
                                               const float* __restrict__ Wq, const float* __restrict__ bq,
                                               const float* __restrict__ Wk, const float* __restrict__ bk,
                                               const float* __restrict__ Wv, const float* __restrict__ bv,
                                               float* __restrict__ q,
                                               float* __restrict__ K,
                                               float* __restrict__ V,
                                               int N, int l) {
    __shared__ float sWq[64 * 64];
    __shared__ float sWk[64 * 64];
    __shared__ float sWv[64 * 64];
    __shared__ float sbq[64], sbk[64], sbv[64];
    for (int i = threadIdx.x; i < 64 * 64; i += 256) {
        sWq[i] = Wq[i]; sWk[i] = Wk[i]; sWv[i] = Wv[i];
    }
    if (threadIdx.x < 64) {
        sbq[threadIdx.x] = bq[threadIdx.x];
        sbk[threadIdx.x] = bk[threadIdx.x];
        sbv[threadIdx.x] = bv[threadIdx.x];
    }
    __syncthreads();
    int row = blockIdx.x * 4 + (threadIdx.x >> 6);
    int c   = threadIdx.x & 63;
    if (row >= N) return;
    const float* xr = xs + (size_t)row * 64;
    float aq = sbq[c], ak = sbk[c], av = sbv[c];
#pragma unroll 16
    for (int k = 0; k < 64; ++k) {
        float xv = xr[k];
        aq = fmaf(xv, sWq[k * 64 + c], aq);
        ak = fmaf(xv, sWk[k * 64 + c], ak);
        av = fmaf(xv, sWv[k * 64 + c], av);
    }
    q[(size_t)row * 64 + c] = aq;
    K[(size_t)row * 192 + l * 64 + c] = ak;
    V[(size_t)row * 192 + l * 64 + c] = av;
}

// One edge per 64-lane wave. lane = head*16 + dd.
__global__ __launch_bounds__(256) void edge_attn_k(const int* __restrict__ src,
                                                   const int* __restrict__ dst,
                                                   const float* __restrict__ dinv,
                                                   const float* __restrict__ q,
                                                   const float* __restrict__ K,
                                                   const float* __restrict__ V,
                                                   float* __restrict__ out,
                                                   int E, int N, int L) {
    int wid  = (blockIdx.x * 256 + threadIdx.x) >> 6;
    int lane = threadIdx.x & 63;
    int etot = E + N;
    if (wid >= etot) return;
    int s, d;
    if (wid < E) { s = src[wid]; d = dst[wid]; }
    else         { s = d = wid - E; }

    float qv = q[(size_t)d * 64 + lane];
    const float* Ks = K + (size_t)s * 192;
    const float* Vs = V + (size_t)s * 192;

    float sc[3];
#pragma unroll
    for (int l = 0; l < 3; ++l) {
        if (l >= L) break;
        float p = qv * Ks[l * 64 + lane];
        // reduce within each 16-lane head group (xor masks 8,4,2,1 stay in-group)
        p += __shfl_xor(p, 8);
        p += __shfl_xor(p, 4);
        p += __shfl_xor(p, 2);
        p += __shfl_xor(p, 1);
        sc[l] = p * 0.25f;   // / sqrt(16)
    }
    float m = sc[0];
#pragma unroll
    for (int l = 1; l < 3; ++l) if (l < L) m = fmaxf(m, sc[l]);
    float w[3];
    float ssum = 0.0f;
#pragma unroll
    for (int l = 0; l < 3; ++l) {
        if (l >= L) break;
        w[l] = expf(sc[l] - m);
        ssum += w[l];
    }
    float inv = 1.0f / ssum;
    float acc = 0.0f;
#pragma unroll
    for (int l = 0; l < 3; ++l) {
        if (l >= L) break;
        acc = fmaf(w[l] * inv, Vs[l * 64 + lane], acc);
    }
    float nrm = dinv[s] * dinv[d];
    atomicAdd(&out[(size_t)d * 64 + lane], acc * nrm);
}

// y[N x 16] = xs[N x 64] @ W[64 x 16] + b
__global__ __launch_bounds__(256) void out_proj_k(const float* __restrict__ xs,
                                                  const float* __restrict__ W,
                                                  const float* __restrict__ b,
                                                  float* __restrict__ y, int N) {
    __shared__ float sW[64 * 16];
    __shared__ float sb[16];
    for (int i = threadIdx.x; i < 64 * 16; i += 256) sW[i] = W[i];
    if (threadIdx.x < 16) sb[threadIdx.x] = b[threadIdx.x];
    __syncthreads();
    int row = blockIdx.x * 16 + (threadIdx.x >> 4);
    int c   = threadIdx.x & 15;
    if (row >= N) return;
    const float* xr = xs + (size_t)row * 64;
    float acc = sb[c];
#pragma unroll 16
    for (int k = 0; k < 64; ++k) acc = fmaf(xr[k], sW[k * 16 + c], acc);
    y[(size_t)row * 16 + c] = acc;
}

extern "C" void kernel_launch(void* const* d_in, const int* in_sizes, int n_in,
                              void* d_out, int out_size, void* d_ws, size_t ws_size,
                              hipStream_t stream) {
    const float* x     = (const float*)d_in[0];
    const int*   ei    = (const int*)d_in[1];
    const float* W_lin = (const float*)d_in[2];
    const float* b_lin = (const float*)d_in[3];
    const float* Wq    = (const float*)d_in[4];
    const float* bq    = (const float*)d_in[5];
    const float* Wk    = (const float*)d_in[6];
    const float* bk    = (const float*)d_in[7];
    const float* Wv    = (const float*)d_in[8];
    const float* bv    = (const float*)d_in[9];
    const float* W_out = (const float*)d_in[10];
    const float* b_out = (const float*)d_in[11];
    float* out = (float*)d_out;

    const int N = in_sizes[0] / 128;
    const int E = in_sizes[1] / 2;
    const int* srcp = ei;
    const int* dstp = ei + E;

    float* ws   = (float*)d_ws;
    float* dinv = ws;
    float* qb   = dinv + N;
    float* Kb   = qb + (size_t)N * 64;
    float* Vb   = Kb + (size_t)N * 192;
    float* sA   = Vb + (size_t)N * 192;
    float* sB   = sA + (size_t)N * 64;

    const int gN   = (N + 255) / 256;
    const int gE   = (E + 255) / 256;
    const int gRow = (N + 3) / 4;   // 4 rows per 256-thread block

    // degree -> dinv
    set_ones_k<<<gN, 256, 0, stream>>>(dinv, N);
    count_deg_k<<<gE, 256, 0, stream>>>(dstp, dinv, E);
    finish_dinv_k<<<gN, 256, 0, stream>>>(dinv, N);

    // h = x @ W_lin + b  -> slice 0
    lin128_64_k<<<gRow, 256, 0, stream>>>(x, W_lin, b_lin, sA, N);

    float* cur = sA;
    float* nxt = sB;
    const int etot = E + N;
    const int gEdge = (etot + 3) / 4;   // 4 waves (edges) per block

    for (int t = 0; t < 3; ++t) {
        // q/K/V from the newest slice (slice index t)
        qkv64_k<<<gRow, 256, 0, stream>>>(cur, Wq, bq, Wk, bk, Wv, bv,
                                          qb, Kb, Vb, N, t);
        hipMemsetAsync(nxt, 0, (size_t)N * 64 * sizeof(float), stream);
        edge_attn_k<<<gEdge, 256, 0, stream>>>(srcp, dstp, dinv, qb, Kb, Vb,
                                               nxt, E, N, t + 1);
        float* tmp = cur; cur = nxt; nxt = tmp;
    }

    out_proj_k<<<gRow, 256, 0, stream>>>(cur, W_out, b_out, out, N);
}

// Round 2
// 973.240 us; speedup vs baseline: 1.0670x; 1.0670x over previous
//
#include <hip/hip_runtime.h>

// ---------------------------------------------------------------------------
// DNANet: 3-layer dynamic-neighborhood-attention graph conv on MI355X.
// N=50000 nodes, E=600000 edges (+N self loops), HID=64, HEADS=4, d=16.
//
// Round-1 restructure: build src-CSR once, then node-per-wave edge kernel.
// K/V[src] live in registers per wave (sequential read once per node) instead
// of being re-gathered per edge; only q[dst] gather + atomic scatter remain
// random.
//
// Workspace layout:
//   dinv       : N floats      rsqrt(in-degree incl self loop)
//   offs       : N+1 ints      src-CSR offsets (doubles as count buffer)
//   cursor     : N ints        scatter cursors
//   dst_sorted : (E+N) ints    dst node id per edge, grouped by src
//   q          : N*64 floats
//   K          : N*192 floats  [node][l][c]
//   V          : N*192 floats
//   sA, sB     : N*64 floats   slice ping-pong
// Total ~118.4 MB.
// ---------------------------------------------------------------------------

__global__ __launch_bounds__(256) void set_ones_f_k(float* __restrict__ p, int n) {
    int i = blockIdx.x * 256 + threadIdx.x;
    if (i < n) p[i] = 1.0f;
}

__global__ __launch_bounds__(256) void set_ones_i_k(int* __restrict__ p, int n) {
    int i = blockIdx.x * 256 + threadIdx.x;
    if (i < n) p[i] = 1;
}

__global__ __launch_bounds__(256) void count_deg_k(const int* __restrict__ dst,
                                                   float* __restrict__ deg, int E) {
    int e = blockIdx.x * 256 + threadIdx.x;
    if (e < E) atomicAdd(&deg[dst[e]], 1.0f);
}

__global__ __launch_bounds__(256) void finish_dinv_k(float* __restrict__ deg, int n) {
    int i = blockIdx.x * 256 + threadIdx.x;
    if (i < n) deg[i] = rsqrtf(deg[i]);
}

__global__ __launch_bounds__(256) void hist_src_k(const int* __restrict__ src,
                                                  int* __restrict__ cnt, int E) {
    int e = blockIdx.x * 256 + threadIdx.x;
    if (e < E) atomicAdd(&cnt[src[e]], 1);
}

// Single-workgroup exclusive scan of offs[0..N) (in place), also fills cursor.
// 1024 threads, shfl-based wave scans + 16-wave LDS combine.
__global__ __launch_bounds__(1024) void scan_offs_k(int* offs, int* cursor, int N) {
    __shared__ int wsum[16];
    __shared__ int woff[16];
    __shared__ int carry_s;
    int tid  = threadIdx.x;
    int lane = tid & 63;
    int w    = tid >> 6;
    if (tid == 0) carry_s = 0;
    __syncthreads();
    for (int base = 0; base < N; base += 1024) {
        int i = base + tid;
        int v = (i < N) ? offs[i] : 0;
        int incl = v;
#pragma unroll
        for (int off = 1; off < 64; off <<= 1) {
            int t = __shfl_up(incl, off);
            if (lane >= off) incl += t;
        }
        if (lane == 63) wsum[w] = incl;
        __syncthreads();
        if (w == 0 && lane < 16) {
            int s  = wsum[lane];
            int si = s;
#pragma unroll
            for (int off = 1; off < 16; off <<= 1) {
                int t = __shfl_up(si, off);
                if (lane >= off) si += t;
            }
            woff[lane] = si - s;           // exclusive wave offset
            if (lane == 15) wsum[0] = si;  // chunk total
        }
        __syncthreads();
        int carry = carry_s;
        int excl  = carry + woff[w] + incl - v;
        if (i < N) { offs[i] = excl; cursor[i] = excl; }
        __syncthreads();
        if (tid == 0) carry_s = carry + wsum[0];
        __syncthreads();
    }
    if (tid == 0) offs[N] = carry_s;
}

__global__ __launch_bounds__(256) void scatter_k(const int* __restrict__ src,
                                                 const int* __restrict__ dst,
                                                 int* __restrict__ cursor,
                                                 int* __restrict__ dst_sorted,
                                                 int E, int N) {
    int e = blockIdx.x * 256 + threadIdx.x;
    int M = E + N;
    if (e >= M) return;
    int s, d;
    if (e < E) { s = src[e]; d = dst[e]; }
    else       { s = d = e - E; }
    int pos = atomicAdd(&cursor[s], 1);
    dst_sorted[pos] = d;
}

// y[N x 64] = x[N x 128] @ W[128 x 64] + b
__global__ __launch_bounds__(256) void lin128_64_k(const float* __restrict__ x,
                                                   const float* __restrict__ W,
                                                   const float* __restrict__ b,
                                                   float* __restrict__ y, int N) {
    __shared__ float sW[128 * 64];
    __shared__ float sb[64];
    for (int i = threadIdx.x; i < 128 * 64; i += 256) sW[i] = W[i];
    if (threadIdx.x < 64) sb[threadIdx.x] = b[threadIdx.x];
    __syncthreads();
    int row = blockIdx.x * 4 + (threadIdx.x >> 6);
    int c   = threadIdx.x & 63;
    if (row >= N) return;
    const float* xr = x + (size_t)row * 128;
    float acc = sb[c];
#pragma unroll 16
    for (int k = 0; k < 128; ++k) acc = fmaf(xr[k], sW[k * 64 + c], acc);
    y[(size_t)row * 64 + c] = acc;
}

// From slice xs (N x 64): q = xs@Wq+bq ; K[:,l,:] = xs@Wk+bk ; V[:,l,:] = xs@Wv+bv
__global__ __launch_bounds__(256) void qkv64_k(const float* __restrict__ xs,
                                               const float* __restrict__ Wq, const float* __restrict__ bq,
                                               const float* __restrict__ Wk, const float* __restrict__ bk,
                                               const float* __restrict__ Wv, const float* __restrict__ bv,
                                               float* __restrict__ q,
                                               float* __restrict__ K,
                                               float* __restrict__ V,
                                               int N, int l) {
    __shared__ float sWq[64 * 64];
    __shared__ float sWk[64 * 64];
    __shared__ float sWv[64 * 64];
    __shared__ float sbq[64], sbk[64], sbv[64];
    for (int i = threadIdx.x; i < 64 * 64; i += 256) {
        sWq[i] = Wq[i]; sWk[i] = Wk[i]; sWv[i] = Wv[i];
    }
    if (threadIdx.x < 64) {
        sbq[threadIdx.x] = bq[threadIdx.x];
        sbk[threadIdx.x] = bk[threadIdx.x];
        sbv[threadIdx.x] = bv[threadIdx.x];
    }
    __syncthreads();
    int row = blockIdx.x * 4 + (threadIdx.x >> 6);
    int c   = threadIdx.x & 63;
    if (row >= N) return;
    const float* xr = xs + (size_t)row * 64;
    float aq = sbq[c], ak = sbk[c], av = sbv[c];
#pragma unroll 16
    for (int k = 0; k < 64; ++k) {
        float xv = xr[k];
        aq = fmaf(xv, sWq[k * 64 + c], aq);
        ak = fmaf(xv, sWk[k * 64 + c], ak);
        av = fmaf(xv, sWv[k * 64 + c], av);
    }
    q[(size_t)row * 64 + c] = aq;
    K[(size_t)row * 192 + l * 64 + c] = ak;
    V[(size_t)row * 192 + l * 64 + c] = av;
}

// One src node per 64-lane wave. K/V slices in registers; dinv[s] folded into V.
template <int L>
__global__ __launch_bounds__(256) void node_attn_k(const int* __restrict__ offs,
                                                   const int* __restrict__ dst_sorted,
                                                   const float* __restrict__ dinv,
                                                   const float* __restrict__ q,
                                                   const float* __restrict__ K,
                                                   const float* __restrict__ V,
                                                   float* __restrict__ out,
                                                   int N) {
    int s    = (blockIdx.x * 256 + threadIdx.x) >> 6;
    int lane = threadIdx.x & 63;
    if (s >= N) return;
    int beg = offs[s], end = offs[s + 1];
    const float* Ks = K + (size_t)s * 192;
    const float* Vs = V + (size_t)s * 192;
    float ds = dinv[s];
    float k0 = Ks[lane],            v0 = Vs[lane] * ds;
    float k1 = 0.f, v1 = 0.f, k2 = 0.f, v2 = 0.f;
    if (L > 1) { k1 = Ks[64 + lane];  v1 = Vs[64 + lane] * ds; }
    if (L > 2) { k2 = Ks[128 + lane]; v2 = Vs[128 + lane] * ds; }

    for (int i = beg; i < end; ++i) {
        int d = dst_sorted[i];
        float qv = q[(size_t)d * 64 + lane];
        float p0 = qv * k0;
        float p1 = (L > 1) ? qv * k1 : 0.f;
        float p2 = (L > 2) ? qv * k2 : 0.f;
#pragma unroll
        for (int m = 8; m >= 1; m >>= 1) {
            p0 += __shfl_xor(p0, m);
            if (L > 1) p1 += __shfl_xor(p1, m);
            if (L > 2) p2 += __shfl_xor(p2, m);
        }
        float s0 = p0 * 0.25f;                       // / sqrt(16)
        float s1 = (L > 1) ? p1 * 0.25f : 0.f;
        float s2 = (L > 2) ? p2 * 0.25f : 0.f;
        float mx = s0;
        if (L > 1) mx = fmaxf(mx, s1);
        if (L > 2) mx = fmaxf(mx, s2);
        float w0 = expf(s0 - mx);
        float w1 = (L > 1) ? expf(s1 - mx) : 0.f;
        float w2 = (L > 2) ? expf(s2 - mx) : 0.f;
        float inv = 1.0f / (w0 + w1 + w2);
        float acc = w0 * v0;
        if (L > 1) acc = fmaf(w1, v1, acc);
        if (L > 2) acc = fmaf(w2, v2, acc);
        float nd = dinv[d];
        atomicAdd(&out[(size_t)d * 64 + lane], acc * inv * nd);
    }
}

// y[N x 16] = xs[N x 64] @ W[64 x 16] + b
__global__ __launch_bounds__(256) void out_proj_k(const float* __restrict__ xs,
                                                  const float* __restrict__ W,
                                                  const float* __restrict__ b,
                                                  float* __restrict__ y, int N) {
    __shared__ float sW[64 * 16];
    __shared__ float sb[16];
    for (int i = threadIdx.x; i < 64 * 16; i += 256) sW[i] = W[i];
    if (threadIdx.x < 16) sb[threadIdx.x] = b[threadIdx.x];
    __syncthreads();
    int row = blockIdx.x * 16 + (threadIdx.x >> 4);
    int c   = threadIdx.x & 15;
    if (row >= N) return;
    const float* xr = xs + (size_t)row * 64;
    float acc = sb[c];
#pragma unroll 16
    for (int k = 0; k < 64; ++k) acc = fmaf(xr[k], sW[k * 16 + c], acc);
    y[(size_t)row * 16 + c] = acc;
}

extern "C" void kernel_launch(void* const* d_in, const int* in_sizes, int n_in,
                              void* d_out, int out_size, void* d_ws, size_t ws_size,
                              hipStream_t stream) {
    const float* x     = (const float*)d_in[0];
    const int*   ei    = (const int*)d_in[1];
    const float* W_lin = (const float*)d_in[2];
    const float* b_lin = (const float*)d_in[3];
    const float* Wq    = (const float*)d_in[4];
    const float* bq    = (const float*)d_in[5];
    const float* Wk    = (const float*)d_in[6];
    const float* bk    = (const float*)d_in[7];
    const float* Wv    = (const float*)d_in[8];
    const float* bv    = (const float*)d_in[9];
    const float* W_out = (const float*)d_in[10];
    const float* b_out = (const float*)d_in[11];
    float* out = (float*)d_out;

    const int N = in_sizes[0] / 128;
    const int E = in_sizes[1] / 2;
    const int M = E + N;
    const int* srcp = ei;
    const int* dstp = ei + E;

    // Workspace carve-up
    char* wsb = (char*)d_ws;
    float* dinv       = (float*)wsb;                    wsb += (size_t)N * sizeof(float);
    int*   offs       = (int*)wsb;                      wsb += (size_t)(N + 1) * sizeof(int);
    int*   cursor     = (int*)wsb;                      wsb += (size_t)N * sizeof(int);
    int*   dst_sorted = (int*)wsb;                      wsb += (size_t)M * sizeof(int);
    float* qb         = (float*)wsb;                    wsb += (size_t)N * 64 * sizeof(float);
    float* Kb         = (float*)wsb;                    wsb += (size_t)N * 192 * sizeof(float);
    float* Vb         = (float*)wsb;                    wsb += (size_t)N * 192 * sizeof(float);
    float* sA         = (float*)wsb;                    wsb += (size_t)N * 64 * sizeof(float);
    float* sB         = (float*)wsb;

    const int gN   = (N + 255) / 256;
    const int gE   = (E + 255) / 256;
    const int gM   = (M + 255) / 256;
    const int gRow = (N + 3) / 4;     // 4 rows per 256-thread block

    // in-degree -> dinv (self loop contributes 1)
    set_ones_f_k<<<gN, 256, 0, stream>>>(dinv, N);
    count_deg_k<<<gE, 256, 0, stream>>>(dstp, dinv, E);
    finish_dinv_k<<<gN, 256, 0, stream>>>(dinv, N);

    // src-CSR: counts (init 1 for self loop) -> scan -> scatter
    set_ones_i_k<<<gN, 256, 0, stream>>>(offs, N);
    hist_src_k<<<gE, 256, 0, stream>>>(srcp, offs, E);
    scan_offs_k<<<1, 1024, 0, stream>>>(offs, cursor, N);
    scatter_k<<<gM, 256, 0, stream>>>(srcp, dstp, cursor, dst_sorted, E, N);

    // h = x @ W_lin + b  -> slice 0
    lin128_64_k<<<gRow, 256, 0, stream>>>(x, W_lin, b_lin, sA, N);

    float* cur = sA;
    float* nxt = sB;

    for (int t = 0; t < 3; ++t) {
        qkv64_k<<<gRow, 256, 0, stream>>>(cur, Wq, bq, Wk, bk, Wv, bv,
                                          qb, Kb, Vb, N, t);
        hipMemsetAsync(nxt, 0, (size_t)N * 64 * sizeof(float), stream);
        switch (t) {
            case 0: node_attn_k<1><<<gRow, 256, 0, stream>>>(offs, dst_sorted, dinv, qb, Kb, Vb, nxt, N); break;
            case 1: node_attn_k<2><<<gRow, 256, 0, stream>>>(offs, dst_sorted, dinv, qb, Kb, Vb, nxt, N); break;
            case 2: node_attn_k<3><<<gRow, 256, 0, stream>>>(offs, dst_sorted, dinv, qb, Kb, Vb, nxt, N); break;
        }
        float* tmp = cur; cur = nxt; nxt = tmp;
    }

    out_proj_k<<<gRow, 256, 0, stream>>>(cur, W_out, b_out, out, N);
}

// Round 3
// 641.762 us; speedup vs baseline: 1.6182x; 1.5165x over previous
//
#include <hip/hip_runtime.h>

// ---------------------------------------------------------------------------
// DNANet round 2: dst-major edge attention (no atomics in the hot path).
// N=50000 nodes, E=600000 edges (+N self loops), HID=64, HEADS=4, d=16.
//
// Pipeline per call:
//   cnt[i]   = in-degree(dst) incl self loop          (int atomics, once)
//   dinv[i]  = rsqrt(cnt[i])
//   dst-CSR  = exclusive-scan(cnt) + cursor scatter -> src_sorted grouped by dst
//   slice0   = x @ W_lin + b
//   3 layers: qkv (KV interleaved, dinv[src] folded into V) -> dst-major attn
//   out      = slice3 @ W_out + b_out
//
// Workspace (~119 MB): dinv N f | cnt N i | offs N+1 i | cursor N i |
//   aux 64 i | src_sorted (E+N) i | q N*64 f | KV N*384 f | sA,sB N*64 f
// ---------------------------------------------------------------------------

__global__ __launch_bounds__(256) void set_ones_i_k(int* __restrict__ p, int n) {
    int i = blockIdx.x * 256 + threadIdx.x;
    if (i < n) p[i] = 1;
}

__global__ __launch_bounds__(256) void hist_dst_k(const int* __restrict__ dst,
                                                  int* __restrict__ cnt, int E) {
    int e = blockIdx.x * 256 + threadIdx.x;
    if (e < E) atomicAdd(&cnt[dst[e]], 1);
}

__global__ __launch_bounds__(256) void dinv_from_cnt_k(const int* __restrict__ cnt,
                                                       float* __restrict__ dinv, int n) {
    int i = blockIdx.x * 256 + threadIdx.x;
    if (i < n) dinv[i] = rsqrtf((float)cnt[i]);
}

// Hierarchical exclusive scan, stage 1: 1024-elem chunks (256 thr x 4).
__global__ __launch_bounds__(256) void scan1_k(const int* __restrict__ cnt,
                                               int* __restrict__ excl,
                                               int* __restrict__ aux, int N) {
    __shared__ int wtot[4];
    int b = blockIdx.x, t = threadIdx.x;
    int lane = t & 63, w = t >> 6;
    int base = b * 1024 + t * 4;
    int v0 = (base + 0 < N) ? cnt[base + 0] : 0;
    int v1 = (base + 1 < N) ? cnt[base + 1] : 0;
    int v2 = (base + 2 < N) ? cnt[base + 2] : 0;
    int v3 = (base + 3 < N) ? cnt[base + 3] : 0;
    int s = v0 + v1 + v2 + v3;
    int incl = s;
#pragma unroll
    for (int off = 1; off < 64; off <<= 1) {
        int u = __shfl_up(incl, off);
        if (lane >= off) incl += u;
    }
    if (lane == 63) wtot[w] = incl;
    __syncthreads();
    int wb = 0;
#pragma unroll
    for (int j = 0; j < 4; ++j) if (j < w) wb += wtot[j];
    int ex = wb + incl - s;
    if (base + 0 < N) excl[base + 0] = ex;
    if (base + 1 < N) excl[base + 1] = ex + v0;
    if (base + 2 < N) excl[base + 2] = ex + v0 + v1;
    if (base + 3 < N) excl[base + 3] = ex + v0 + v1 + v2;
    if (t == 0) aux[b] = wtot[0] + wtot[1] + wtot[2] + wtot[3];
}

// Stage 2: single-wave scan of chunk totals (nb <= 64; N <= 65536).
__global__ __launch_bounds__(64) void scan_aux_k(int* __restrict__ aux, int nb,
                                                 int* __restrict__ total) {
    int lane = threadIdx.x;
    int v = (lane < nb) ? aux[lane] : 0;
    int incl = v;
#pragma unroll
    for (int off = 1; off < 64; off <<= 1) {
        int u = __shfl_up(incl, off);
        if (lane >= off) incl += u;
    }
    if (lane < nb) aux[lane] = incl - v;
    if (lane == 63) total[0] = incl;
}

// Stage 3: add chunk bases; mirror into cursor.
__global__ __launch_bounds__(256) void scan_add_k(int* __restrict__ offs,
                                                  const int* __restrict__ aux,
                                                  int* __restrict__ cursor, int N) {
    int i = blockIdx.x * 256 + threadIdx.x;
    if (i < N) {
        int o = offs[i] + aux[i >> 10];
        offs[i] = o;
        cursor[i] = o;
    }
}

__global__ __launch_bounds__(256) void scatter_dst_k(const int* __restrict__ src,
                                                     const int* __restrict__ dst,
                                                     int* __restrict__ cursor,
                                                     int* __restrict__ src_sorted,
                                                     int E, int N) {
    int e = blockIdx.x * 256 + threadIdx.x;
    int M = E + N;
    if (e >= M) return;
    int s, d;
    if (e < E) { s = src[e]; d = dst[e]; }
    else       { s = d = e - E; }
    int pos = atomicAdd(&cursor[d], 1);
    src_sorted[pos] = s;
}

// y[N x 64] = x[N x 128] @ W[128 x 64] + b
__global__ __launch_bounds__(256) void lin128_64_k(const float* __restrict__ x,
                                                   const float* __restrict__ W,
                                                   const float* __restrict__ b,
                                                   float* __restrict__ y, int N) {
    __shared__ float sW[128 * 64];
    __shared__ float sb[64];
    for (int i = threadIdx.x; i < 128 * 64; i += 256) sW[i] = W[i];
    if (threadIdx.x < 64) sb[threadIdx.x] = b[threadIdx.x];
    __syncthreads();
    int row = blockIdx.x * 4 + (threadIdx.x >> 6);
    int c   = threadIdx.x & 63;
    if (row >= N) return;
    const float* xr = x + (size_t)row * 128;
    float acc = sb[c];
#pragma unroll 16
    for (int k = 0; k < 128; ++k) acc = fmaf(xr[k], sW[k * 64 + c], acc);
    y[(size_t)row * 64 + c] = acc;
}

// From slice xs (N x 64): q = xs@Wq+bq ; KV[:,l,0,:] = xs@Wk+bk ;
// KV[:,l,1,:] = (xs@Wv+bv) * dinv   (dinv[src] folded into V)
__global__ __launch_bounds__(256) void qkv64_k(const float* __restrict__ xs,
                                               const float* __restrict__ Wq, const float* __restrict__ bq,
                                               const float* __restrict__ Wk, const float* __restrict__ bk,
                                               const float* __restrict__ Wv, const float* __restrict__ bv,
                                               const float* __restrict__ dinv,
                                               float* __restrict__ q,
                                               float* __restrict__ KV,
                                               int N, int l) {
    __shared__ float sWq[64 * 64];
    __shared__ float sWk[64 * 64];
    __shared__ float sWv[64 * 64];
    __shared__ float sbq[64], sbk[64], sbv[64];
    for (int i = threadIdx.x; i < 64 * 64; i += 256) {
        sWq[i] = Wq[i]; sWk[i] = Wk[i]; sWv[i] = Wv[i];
    }
    if (threadIdx.x < 64) {
        sbq[threadIdx.x] = bq[threadIdx.x];
        sbk[threadIdx.x] = bk[threadIdx.x];
        sbv[threadIdx.x] = bv[threadIdx.x];
    }
    __syncthreads();
    int row = blockIdx.x * 4 + (threadIdx.x >> 6);
    int c   = threadIdx.x & 63;
    if (row >= N) return;
    const float* xr = xs + (size_t)row * 64;
    float aq = sbq[c], ak = sbk[c], av = sbv[c];
#pragma unroll 16
    for (int k = 0; k < 64; ++k) {
        float xv = xr[k];
        aq = fmaf(xv, sWq[k * 64 + c], aq);
        ak = fmaf(xv, sWk[k * 64 + c], ak);
        av = fmaf(xv, sWv[k * 64 + c], av);
    }
    q[(size_t)row * 64 + c] = aq;
    float* kvp = KV + (size_t)row * 384 + l * 128;
    kvp[c]      = ak;
    kvp[64 + c] = av * dinv[row];
}

// One dst node per 64-lane wave; q in regs, gather K/V[src], register
// accumulate, single coalesced write. No atomics.
template <int L>
__global__ __launch_bounds__(256) void attn_dst_k(const int* __restrict__ offs,
                                                  const int* __restrict__ src_sorted,
                                                  const float* __restrict__ dinv,
                                                  const float* __restrict__ q,
                                                  const float* __restrict__ KV,
                                                  float* __restrict__ out,
                                                  int N) {
    int d    = (blockIdx.x * 256 + threadIdx.x) >> 6;
    int lane = threadIdx.x & 63;
    if (d >= N) return;
    int beg = offs[d], end = offs[d + 1];
    float qv  = (L > 1) ? q[(size_t)d * 64 + lane] : 0.0f;
    float acc = 0.0f;

    for (int base = bool(1) ? beg : 0; base < end; base += 64) {
        int m = end - base;
        if (m > 64) m = 64;
        int sid = (base + lane < end) ? src_sorted[base + lane] : 0;
        for (int i = 0; i < m; ++i) {
            int s = __shfl(sid, i);
            const float* p = KV + (size_t)s * 384;
            if (L == 1) {
                acc += p[64 + lane];          // softmax over 1 slice == 1
                continue;
            }
            float v0 = p[64 + lane];
            float p0 = qv * p[lane];
            float p1 = 0.f, p2 = 0.f, v1 = 0.f, v2 = 0.f;
            if (L > 1) { p1 = qv * p[128 + lane]; v1 = p[192 + lane]; }
            if (L > 2) { p2 = qv * p[256 + lane]; v2 = p[320 + lane]; }
#pragma unroll
            for (int mm = 8; mm >= 1; mm >>= 1) {
                p0 += __shfl_xor(p0, mm);
                if (L > 1) p1 += __shfl_xor(p1, mm);
                if (L > 2) p2 += __shfl_xor(p2, mm);
            }
            float s0 = p0 * 0.25f;            // / sqrt(16)
            float s1 = p1 * 0.25f;
            float s2 = p2 * 0.25f;
            float mx = s0;
            if (L > 1) mx = fmaxf(mx, s1);
            if (L > 2) mx = fmaxf(mx, s2);
            float w0 = __expf(s0 - mx);
            float w1 = (L > 1) ? __expf(s1 - mx) : 0.f;
            float w2 = (L > 2) ? __expf(s2 - mx) : 0.f;
            float inv = __builtin_amdgcn_rcpf(w0 + w1 + w2);
            float msg = w0 * v0;
            if (L > 1) msg = fmaf(w1, v1, msg);
            if (L > 2) msg = fmaf(w2, v2, msg);
            acc = fmaf(msg, inv, acc);
        }
    }
    out[(size_t)d * 64 + lane] = acc * dinv[d];
}

// y[N x 16] = xs[N x 64] @ W[64 x 16] + b
__global__ __launch_bounds__(256) void out_proj_k(const float* __restrict__ xs,
                                                  const float* __restrict__ W,
                                                  const float* __restrict__ b,
                                                  float* __restrict__ y, int N) {
    __shared__ float sW[64 * 16];
    __shared__ float sb[16];
    for (int i = threadIdx.x; i < 64 * 16; i += 256) sW[i] = W[i];
    if (threadIdx.x < 16) sb[threadIdx.x] = b[threadIdx.x];
    __syncthreads();
    int row = blockIdx.x * 16 + (threadIdx.x >> 4);
    int c   = threadIdx.x & 15;
    if (row >= N) return;
    const float* xr = xs + (size_t)row * 64;
    float acc = sb[c];
#pragma unroll 16
    for (int k = 0; k < 64; ++k) acc = fmaf(xr[k], sW[k * 16 + c], acc);
    y[(size_t)row * 16 + c] = acc;
}

extern "C" void kernel_launch(void* const* d_in, const int* in_sizes, int n_in,
                              void* d_out, int out_size, void* d_ws, size_t ws_size,
                              hipStream_t stream) {
    const float* x     = (const float*)d_in[0];
    const int*   ei    = (const int*)d_in[1];
    const float* W_lin = (const float*)d_in[2];
    const float* b_lin = (const float*)d_in[3];
    const float* Wq    = (const float*)d_in[4];
    const float* bq    = (const float*)d_in[5];
    const float* Wk    = (const float*)d_in[6];
    const float* bk    = (const float*)d_in[7];
    const float* Wv    = (const float*)d_in[8];
    const float* bv    = (const float*)d_in[9];
    const float* W_out = (const float*)d_in[10];
    const float* b_out = (const float*)d_in[11];
    float* out = (float*)d_out;

    const int N = in_sizes[0] / 128;
    const int E = in_sizes[1] / 2;
    const int M = E + N;
    const int* srcp = ei;
    const int* dstp = ei + E;

    char* wsb = (char*)d_ws;
    float* dinv       = (float*)wsb;  wsb += (size_t)N * sizeof(float);
    int*   cnt        = (int*)wsb;    wsb += (size_t)N * sizeof(int);
    int*   offs       = (int*)wsb;    wsb += (size_t)(N + 1) * sizeof(int);
    int*   cursor     = (int*)wsb;    wsb += (size_t)N * sizeof(int);
    int*   aux        = (int*)wsb;    wsb += 64 * sizeof(int);
    int*   src_sorted = (int*)wsb;    wsb += (size_t)M * sizeof(int);
    float* qb         = (float*)wsb;  wsb += (size_t)N * 64 * sizeof(float);
    float* KVb        = (float*)wsb;  wsb += (size_t)N * 384 * sizeof(float);
    float* sA         = (float*)wsb;  wsb += (size_t)N * 64 * sizeof(float);
    float* sB         = (float*)wsb;

    const int gN   = (N + 255) / 256;
    const int gE   = (E + 255) / 256;
    const int gM   = (M + 255) / 256;
    const int gRow = (N + 3) / 4;          // 4 waves (rows/nodes) per block
    const int nb   = (N + 1023) / 1024;    // scan chunks (<= 64 for N <= 65536)

    // in-degree (incl self loop) -> dinv, and dst-CSR
    set_ones_i_k<<<gN, 256, 0, stream>>>(cnt, N);
    hist_dst_k<<<gE, 256, 0, stream>>>(dstp, cnt, E);
    dinv_from_cnt_k<<<gN, 256, 0, stream>>>(cnt, dinv, N);
    scan1_k<<<nb, 256, 0, stream>>>(cnt, offs, aux, N);
    scan_aux_k<<<1, 64, 0, stream>>>(aux, nb, offs + N);
    scan_add_k<<<gN, 256, 0, stream>>>(offs, aux, cursor, N);
    scatter_dst_k<<<gM, 256, 0, stream>>>(srcp, dstp, cursor, src_sorted, E, N);

    // slice 0
    lin128_64_k<<<gRow, 256, 0, stream>>>(x, W_lin, b_lin, sA, N);

    float* cur = sA;
    float* nxt = sB;
    for (int t = 0; t < 3; ++t) {
        qkv64_k<<<gRow, 256, 0, stream>>>(cur, Wq, bq, Wk, bk, Wv, bv, dinv,
                                          qb, KVb, N, t);
        switch (t) {
            case 0: attn_dst_k<1><<<gRow, 256, 0, stream>>>(offs, src_sorted, dinv, qb, KVb, nxt, N); break;
            case 1: attn_dst_k<2><<<gRow, 256, 0, stream>>>(offs, src_sorted, dinv, qb, KVb, nxt, N); break;
            case 2: attn_dst_k<3><<<gRow, 256, 0, stream>>>(offs, src_sorted, dinv, qb, KVb, nxt, N); break;
        }
        float* tmp = cur; cur = nxt; nxt = tmp;
    }

    out_proj_k<<<gRow, 256, 0, stream>>>(cur, W_out, b_out, out, N);
}